// Round 5
// baseline (196.556 us; speedup 1.0000x reference)
//
#include <hip/hip_runtime.h>

#define Bn 8
#define Nn 16384
#define Cn 256
#define NC 32              // split-K chunks over N (gram)
#define XPB ((size_t)8388608)   // bytes per batch in packed xp (256*16384*2)

typedef __attribute__((ext_vector_type(4)))  float f32x4;
typedef __attribute__((ext_vector_type(16))) float f32x16;
typedef __attribute__((ext_vector_type(8)))  __bf16 bf16x8;
typedef __attribute__((ext_vector_type(8)))  _Float16 f16x8;
typedef __attribute__((ext_vector_type(8)))  unsigned short u16x8;

static __device__ __forceinline__ unsigned short f2bf(float f) {
    unsigned int u = __float_as_uint(f);
    u += 0x7fff + ((u >> 16) & 1);          // RNE
    return (unsigned short)(u >> 16);
}
static __device__ __forceinline__ unsigned short f2h(float f) {
    return __builtin_bit_cast(unsigned short, (_Float16)f);
}
static __device__ __forceinline__ f32x16 mfma16h(u16x8 a, u16x8 b, f32x16 c) {
    return __builtin_amdgcn_mfma_f32_32x32x16_f16(
        __builtin_bit_cast(f16x8, a), __builtin_bit_cast(f16x8, b), c, 0, 0, 0);
}
static __device__ __forceinline__ f32x16 mfma16b(u16x8 a, u16x8 b, f32x16 c) {
    return __builtin_amdgcn_mfma_f32_32x32x16_bf16(
        __builtin_bit_cast(bf16x8, a), __builtin_bit_cast(bf16x8, b), c, 0, 0, 0);
}

// ---------------- K0 (k_pack): x [C][N] fp32 -> swizzled fp16 tiles + row sums ----------
// Tile nt = n>>7: [256 c][16 slots][8 shorts], 64KB contiguous. slot = (n128>>3)^(c&15).
// Block = (b, c8 of 8 rows, nq of 4096 n): reads 8 x 16KB streams, writes 32 x 2KB chunks/tile.
__global__ __launch_bounds__(256, 2) void k_pack(
    const float* __restrict__ x, unsigned short* __restrict__ xp,
    float* __restrict__ spart) {
  const int blk = blockIdx.x;
  const int nq  = blk & 3;
  const int c8  = (blk >> 2) & 31;
  const int b   = blk >> 7;
  const int t   = threadIdx.x;
  const int row = t >> 5;          // 0..7
  const int l32 = t & 31;
  const int c   = c8 * 8 + row;

  __shared__ unsigned short lx[8][4096];

  const float* src = x + (size_t)b * (Cn * Nn) + (size_t)c * Nn + nq * 4096;
  float srow = 0.f;
#pragma unroll 4
  for (int it = 0; it < 32; ++it) {
    int n = it * 128 + l32 * 4;
    f32x4 v = *(const f32x4*)(src + n);
    srow += v.x + v.y + v.z + v.w;
    ushort4 h = make_ushort4(f2h(v.x), f2h(v.y), f2h(v.z), f2h(v.w));
    *(ushort4*)(&lx[row][n]) = h;
  }
  srow += __shfl_xor(srow, 1, 32);
  srow += __shfl_xor(srow, 2, 32);
  srow += __shfl_xor(srow, 4, 32);
  srow += __shfl_xor(srow, 8, 32);
  srow += __shfl_xor(srow, 16, 32);
  if (l32 == 0) spart[(b * 4 + nq) * Cn + c] = srow;
  __syncthreads();

  char* dstb = (char*)xp + (size_t)b * XPB;
  const int n0   = l32 * 4;                       // 0..124
  const int slot = ((n0 >> 3) ^ (c & 15)) & 15;
  const size_t woff = (size_t)c * 256 + slot * 16 + (n0 & 7) * 2;
#pragma unroll 4
  for (int ntl = 0; ntl < 32; ++ntl) {
    int nt = nq * 32 + ntl;
    ushort4 val = *(const ushort4*)(&lx[row][ntl * 128 + n0]);
    *(ushort4*)(dstb + (size_t)nt * 65536 + woff) = val;
  }
}

// ---------------- K1 (k_gram): Gram partials from packed tiles (fp16 MFMA) ----------------
// grid = Bn*NC*2 (row halves); 512 thr = 8 waves (2 row-groups x 4 col-groups), acc[2][2].
// Stage = one 64KB tile (K=128), verbatim contiguous copy -> LDS; 4 stages per block.
__global__ __launch_bounds__(512, 4) void k_gram(
    const unsigned short* __restrict__ xp, float* __restrict__ gpart) {
  const int blk  = blockIdx.x;
  const int half = blk & 1;
  const int ck   = (blk >> 1) & (NC - 1);
  const int b    = blk >> 6;
  const char* tb0 = (const char*)xp + (size_t)b * XPB + (size_t)(ck * 4) * 65536;

  __shared__ __align__(16) char smem[65536];

  const int t    = threadIdx.x;
  const int lane = t & 63;
  const int w    = t >> 6;
  const int wm = w & 1, wn = w >> 1;
  const int ln = lane & 31, kh = lane >> 5;

  f32x16 acc[2][2];
#pragma unroll
  for (int m = 0; m < 2; ++m)
#pragma unroll
    for (int n = 0; n < 2; ++n)
#pragma unroll
      for (int i = 0; i < 16; ++i) acc[m][n][i] = 0.f;

  u16x8 ldreg[8];
#pragma unroll
  for (int r = 0; r < 8; ++r)
    ldreg[r] = *(const u16x8*)(tb0 + r * 8192 + t * 16);

  for (int st = 0; st < 4; ++st) {
    // regs -> LDS (waits the global loads; issue-early/write-late)
#pragma unroll
    for (int r = 0; r < 8; ++r)
      *(u16x8*)(smem + r * 8192 + t * 16) = ldreg[r];
    __syncthreads();
    if (st < 3) {                      // issue next tile's loads; in flight across MFMA
#pragma unroll
      for (int r = 0; r < 8; ++r)
        ldreg[r] = *(const u16x8*)(tb0 + (st + 1) * 65536 + r * 8192 + t * 16);
    }
#pragma unroll
    for (int sl = 0; sl < 8; ++sl) {
      const int ch = sl * 2 + kh;      // 16B k-chunk index
      u16x8 A[2], Bv[2];
#pragma unroll
      for (int m = 0; m < 2; ++m) {
        int r = half * 128 + wm * 64 + m * 32 + ln;
        A[m] = *(const u16x8*)(smem + r * 256 + ((ch ^ (r & 15)) << 4));
      }
#pragma unroll
      for (int n = 0; n < 2; ++n) {
        int r = wn * 64 + n * 32 + ln;
        Bv[n] = *(const u16x8*)(smem + r * 256 + ((ch ^ (r & 15)) << 4));
      }
#pragma unroll
      for (int m = 0; m < 2; ++m)
#pragma unroll
        for (int n = 0; n < 2; ++n)
          acc[m][n] = mfma16h(A[m], Bv[n], acc[m][n]);
    }
    __syncthreads();
  }

  float* gp = gpart + (size_t)(b * NC + ck) * (Cn * Cn);
#pragma unroll
  for (int m = 0; m < 2; ++m)
#pragma unroll
    for (int n = 0; n < 2; ++n)
#pragma unroll
      for (int r2 = 0; r2 < 16; ++r2) {
        int row = half * 128 + wm * 64 + m * 32 + (r2 & 3) + 8 * (r2 >> 2) + 4 * kh;
        int col = wn * 64 + n * 32 + ln;
        gp[row * Cn + col] = acc[m][n][r2];
      }
}

// ---------------- K2 (k_misc, 8 blocks): sv, wkT transpose, kN = Wk s + N bk ----------------
__global__ __launch_bounds__(256) void k_misc(
    const float* __restrict__ spart, const float* __restrict__ wk,
    const float* __restrict__ bk, float* __restrict__ sv,
    float* __restrict__ wkT, float* __restrict__ kN) {
  const int bb = blockIdx.x, t = threadIdx.x;
  __shared__ float s_l[256];
  float a = 0.f;
#pragma unroll
  for (int q = 0; q < 4; ++q) a += spart[(bb * 4 + q) * Cn + t];
  sv[bb * Cn + t] = a;
  s_l[t] = a;
#pragma unroll
  for (int j = 0; j < 32; ++j) {
    int k = bb * 32 + j;
    wkT[k * Cn + t] = wk[t * Cn + k];
  }
  __syncthreads();
  float k2 = 0.f;
  for (int c = 0; c < 256; ++c) k2 += wk[t * Cn + c] * s_l[c];
  kN[bb * Cn + t] = k2 + 16384.f * bk[t];
}

// ---------------- K3 (k_gk): GK = (sum gpart) @ WkT + s*bk^T  (fp32 VALU) ----------------
// grid = Bn*64 (4-row tiles, 2 blocks/CU). Fuses the gpart reduction.
__global__ __launch_bounds__(256) void k_gk(
    const float* __restrict__ gpart, const float* __restrict__ sv,
    const float* __restrict__ wkT, const float* __restrict__ bk,
    float* __restrict__ GK) {
  const int b = blockIdx.x >> 6, tile = blockIdx.x & 63;
  const int r0 = tile * 4, t = threadIdx.x;
  __shared__ float g_l[4][256];

  float a[4] = {0.f, 0.f, 0.f, 0.f};
  const float* gp = gpart + (size_t)b * NC * 65536 + r0 * 256 + t;
  for (int ck = 0; ck < NC; ++ck) {
#pragma unroll
    for (int j = 0; j < 4; ++j) a[j] += gp[(size_t)ck * 65536 + j * 256];
  }
#pragma unroll
  for (int j = 0; j < 4; ++j) g_l[j][t] = a[j];
  __syncthreads();

  float acc[4] = {0.f, 0.f, 0.f, 0.f};
  for (int k0 = 0; k0 < 256; k0 += 4) {
    float w0 = wkT[(k0 + 0) * 256 + t];
    float w1 = wkT[(k0 + 1) * 256 + t];
    float w2 = wkT[(k0 + 2) * 256 + t];
    float w3 = wkT[(k0 + 3) * 256 + t];
#pragma unroll
    for (int r = 0; r < 4; ++r) {
      f32x4 gv = *(const f32x4*)(&g_l[r][k0]);
      acc[r] += gv.x * w0 + gv.y * w1 + gv.z * w2 + gv.w * w3;
    }
  }
  float bkt = bk[t];
#pragma unroll
  for (int r = 0; r < 4; ++r) {
    float svr = sv[b * 256 + r0 + r];
    GK[((size_t)b * 256 + r0 + r) * 256 + t] = acc[r] + svr * bkt;
  }
}

// ---------------- K4 (k_scores): scores = Wq@GK + bq*kN^T; softmax; ccB(+I) bf16 ----------------
__global__ __launch_bounds__(256) void k_scores(
    const float* __restrict__ wq, const float* __restrict__ GK,
    const float* __restrict__ bq, const float* __restrict__ kN,
    unsigned short* __restrict__ ccB) {
  const int b    = blockIdx.x >> 5;
  const int tile = blockIdx.x & 31;
  const int c0   = tile * 8;
  const int t    = threadIdx.x;

  __shared__ float wq_l[8][256];
  __shared__ float sc_l[8][256];
  __shared__ unsigned short cct_l[256][8];

#pragma unroll
  for (int j = 0; j < 8; ++j) wq_l[j][t] = wq[(c0 + j) * Cn + t];
  __syncthreads();

  float acc[8];
#pragma unroll
  for (int r = 0; r < 8; ++r) acc[r] = 0.f;
  for (int k0 = 0; k0 < 256; k0 += 4) {
    float g0 = GK[((size_t)b * 256 + k0 + 0) * 256 + t];
    float g1 = GK[((size_t)b * 256 + k0 + 1) * 256 + t];
    float g2 = GK[((size_t)b * 256 + k0 + 2) * 256 + t];
    float g3 = GK[((size_t)b * 256 + k0 + 3) * 256 + t];
#pragma unroll
    for (int r = 0; r < 8; ++r) {
      f32x4 qv = *(const f32x4*)(&wq_l[r][k0]);
      acc[r] += qv.x * g0 + qv.y * g1 + qv.z * g2 + qv.w * g3;
    }
  }
  float kNt = kN[b * 256 + t];
#pragma unroll
  for (int r = 0; r < 8; ++r) sc_l[r][t] = acc[r] + bq[c0 + r] * kNt;
  __syncthreads();

  const int r = t >> 5, sub = t & 31;
  float v[8];
#pragma unroll
  for (int j = 0; j < 8; ++j) v[j] = sc_l[r][sub + 32 * j];
  float mx = v[0];
#pragma unroll
  for (int j = 1; j < 8; ++j) mx = fmaxf(mx, v[j]);
#pragma unroll
  for (int msk = 16; msk >= 1; msk >>= 1) mx = fmaxf(mx, __shfl_xor(mx, msk, 32));
  float se = 0.f;
#pragma unroll
  for (int j = 0; j < 8; ++j) { v[j] = __expf(v[j] - mx); se += v[j]; }
#pragma unroll
  for (int msk = 16; msk >= 1; msk >>= 1) se += __shfl_xor(se, msk, 32);
  float inv = 1.f / se;
#pragma unroll
  for (int j = 0; j < 8; ++j) {
    int d = sub + 32 * j;
    float cc = v[j] * inv + ((d == c0 + r) ? 1.f : 0.f);   // fold residual: cc + I
    cct_l[d][r] = f2bf(cc);
  }
  __syncthreads();
  *(uint4*)(ccB + (size_t)b * 65536 + (size_t)(tile * 256 + t) * 8) =
      *(const uint4*)(&cct_l[t][0]);
}

// ---------------- K5 (k_out): out = x_bf16 @ (cc + I) ----------------
__global__ __launch_bounds__(256, 4) void k_out(
    const float* __restrict__ x, const unsigned short* __restrict__ ccB,
    float* __restrict__ out) {
  const int blk = blockIdx.x;
  const int b  = blk >> 8;
  const int n0 = (blk & 255) * 64;
  const float* xb = x + (size_t)b * Nn * Cn + (size_t)n0 * Cn;
  const unsigned short* cb = ccB + (size_t)b * 65536;
  float* ob = out + (size_t)b * Nn * Cn + (size_t)n0 * Cn;

  __shared__ __align__(16) char smem[32768];   // [64 rows][512B] bf16, XOR-swizzled

  const int t    = threadIdx.x;
  const int lane = t & 63;
  const int w    = t >> 6;
  const int ln = lane & 31;
  const int kh = lane >> 5;

  f32x16 acc[2][2];
#pragma unroll
  for (int m = 0; m < 2; ++m)
#pragma unroll
    for (int n = 0; n < 2; ++n)
#pragma unroll
      for (int i = 0; i < 16; ++i) acc[m][n][i] = 0.f;

#pragma unroll
  for (int i = 0; i < 16; ++i) {
    int fi = i * 256 + t;
    f32x4 v = *(const f32x4*)(xb + (size_t)fi * 4);
    int row = fi >> 6, c = fi & 63;
    ushort4 hv = make_ushort4(f2bf(v.x), f2bf(v.y), f2bf(v.z), f2bf(v.w));
    *(ushort4*)(smem + row * 512 + ((c * 8) ^ ((row & 31) << 4))) = hv;
  }
  __syncthreads();

#pragma unroll
  for (int ks = 0; ks < 16; ++ks) {
    u16x8 A[2], Bv[2];
    const int g = ks * 2 + kh;
#pragma unroll
    for (int m = 0; m < 2; ++m) {
      int row = m * 32 + ln;
      A[m] = *(const u16x8*)(smem + row * 512 + ((g * 16) ^ ((row & 31) << 4)));
    }
#pragma unroll
    for (int n = 0; n < 2; ++n) {
      int d = w * 64 + n * 32 + ln;
      Bv[n] = *(const u16x8*)(cb + (size_t)g * 2048 + (size_t)d * 8);
    }
#pragma unroll
    for (int m = 0; m < 2; ++m)
#pragma unroll
      for (int n = 0; n < 2; ++n)
        acc[m][n] = mfma16b(A[m], Bv[n], acc[m][n]);
  }

#pragma unroll
  for (int m = 0; m < 2; ++m)
#pragma unroll
    for (int n = 0; n < 2; ++n)
#pragma unroll
      for (int r2 = 0; r2 < 16; ++r2) {
        int row = m * 32 + (r2 & 3) + 8 * (r2 >> 2) + 4 * kh;
        int col = w * 64 + n * 32 + ln;
        ob[(size_t)row * Cn + col] = acc[m][n][r2];
      }
}

extern "C" void kernel_launch(void* const* d_in, const int* in_sizes, int n_in,
                              void* d_out, int out_size, void* d_ws, size_t ws_size,
                              hipStream_t stream) {
  const float* x  = (const float*)d_in[0];
  const float* wq = (const float*)d_in[1];
  const float* bq = (const float*)d_in[2];
  const float* wk = (const float*)d_in[3];
  const float* bk = (const float*)d_in[4];
  float* out = (float*)d_out;

  unsigned short* xp = (unsigned short*)d_ws;                    // 67MB packed fp16
  float* gpart = (float*)((char*)d_ws + (size_t)Bn * XPB);       // [B][NC][256][256] 64MB
  float* spart = gpart + (size_t)Bn * NC * 65536;                // [B][4][256]
  float* sv    = spart + (size_t)Bn * 4 * 256;                   // [B][256]
  float* wkT   = sv + (size_t)Bn * 256;                          // [256][256]
  float* kN    = wkT + 65536;                                    // [B][256]
  float* GK    = kN + (size_t)Bn * 256;                          // [B][256][256]
  unsigned short* ccB = (unsigned short*)(GK + (size_t)Bn * 65536); // [B][32][256][8] bf16

  hipLaunchKernelGGL(k_pack,   dim3(Bn * 128),    dim3(256), 0, stream, x, xp, spart);
  hipLaunchKernelGGL(k_gram,   dim3(Bn * NC * 2), dim3(512), 0, stream, xp, gpart);
  hipLaunchKernelGGL(k_misc,   dim3(Bn),          dim3(256), 0, stream, spart, wk, bk, sv, wkT, kN);
  hipLaunchKernelGGL(k_gk,     dim3(Bn * 64),     dim3(256), 0, stream, gpart, sv, wkT, bk, GK);
  hipLaunchKernelGGL(k_scores, dim3(Bn * 32),     dim3(256), 0, stream, wq, GK, bq, kN, ccB);
  hipLaunchKernelGGL(k_out,    dim3(Bn * 256),    dim3(256), 0, stream, x, ccB, out);
}

// Round 6
// 176.262 us; speedup vs baseline: 1.1151x; 1.1151x over previous
//
#include <hip/hip_runtime.h>

#define Bn 8
#define Nn 16384
#define Cn 256
#define NC 32                   // split-K chunks over N (gram); K=512 per block
#define XPB ((size_t)8388608)   // bytes per batch in packed xp (256*16384*2)

typedef __attribute__((ext_vector_type(4)))  float f32x4;
typedef __attribute__((ext_vector_type(16))) float f32x16;
typedef __attribute__((ext_vector_type(8)))  __bf16 bf16x8;
typedef __attribute__((ext_vector_type(8)))  _Float16 f16x8;
typedef __attribute__((ext_vector_type(8)))  unsigned short u16x8;

static __device__ __forceinline__ unsigned short f2bf(float f) {
    unsigned int u = __float_as_uint(f);
    u += 0x7fff + ((u >> 16) & 1);          // RNE
    return (unsigned short)(u >> 16);
}
static __device__ __forceinline__ unsigned short f2h(float f) {
    return __builtin_bit_cast(unsigned short, (_Float16)f);
}
static __device__ __forceinline__ f32x16 mfma16h(u16x8 a, u16x8 b, f32x16 c) {
    return __builtin_amdgcn_mfma_f32_32x32x16_f16(
        __builtin_bit_cast(f16x8, a), __builtin_bit_cast(f16x8, b), c, 0, 0, 0);
}
static __device__ __forceinline__ f32x16 mfma16b(u16x8 a, u16x8 b, f32x16 c) {
    return __builtin_amdgcn_mfma_f32_32x32x16_bf16(
        __builtin_bit_cast(bf16x8, a), __builtin_bit_cast(bf16x8, b), c, 0, 0, 0);
}

// ---------------- K0 (k_pack): x [C][N] fp32 -> swizzled fp16 K-tiles + row sums ----------
// Tile nt = n>>7: [256 c][16 slots][16B], 64KB contiguous; slot s holds chunk ch = s^(c&15).
// LDS-free: lane = (c-row, slot); reads 32B contiguous, writes 16B; no barriers.
// Row sums accumulate into sv via atomicAdd (sv pre-zeroed by hipMemsetAsync).
__global__ __launch_bounds__(256) void k_pack(
    const float* __restrict__ x, unsigned short* __restrict__ xp,
    float* __restrict__ sv) {
  const int blk = blockIdx.x;
  const int nr  = blk & 7;            // 2048-wide n range (16 tiles)
  const int c16 = (blk >> 3) & 15;    // 16-row stripe
  const int b   = blk >> 7;
  const int t   = threadIdx.x;
  const int s   = t & 15;             // slot
  const int cr  = t >> 4;             // row within stripe
  const int c   = c16 * 16 + cr;
  const int ch  = s ^ (c & 15);       // k-chunk stored in this slot

  const float* src = x + (size_t)b * (Cn * Nn) + (size_t)c * Nn + nr * 2048 + ch * 8;
  char* dst = (char*)xp + (size_t)b * XPB + (size_t)(nr * 16) * 65536
            + (size_t)c * 256 + s * 16;

  float srow = 0.f;
#pragma unroll 4
  for (int i = 0; i < 16; ++i) {
    f32x4 v0 = *(const f32x4*)(src + (size_t)i * 128);
    f32x4 v1 = *(const f32x4*)(src + (size_t)i * 128 + 4);
    srow += (v0.x + v0.y + v0.z + v0.w) + (v1.x + v1.y + v1.z + v1.w);
    uint4 o;
    o.x = (unsigned)f2h(v0.x) | ((unsigned)f2h(v0.y) << 16);
    o.y = (unsigned)f2h(v0.z) | ((unsigned)f2h(v0.w) << 16);
    o.z = (unsigned)f2h(v1.x) | ((unsigned)f2h(v1.y) << 16);
    o.w = (unsigned)f2h(v1.z) | ((unsigned)f2h(v1.w) << 16);
    *(uint4*)(dst + (size_t)i * 65536) = o;
  }
  // reduce the 16 slot-lanes sharing row c
  srow += __shfl_xor(srow, 1, 16);
  srow += __shfl_xor(srow, 2, 16);
  srow += __shfl_xor(srow, 4, 16);
  srow += __shfl_xor(srow, 8, 16);
  if (s == 0) atomicAdd(&sv[b * Cn + c], srow);
}

// ---------------- K1 (k_gram): G-partial 256x256 per block from packed tiles ----------------
// 256 blocks (XCD-chunked: 1 batch per XCD). 512 thr = 8 waves (2 row x 4 col), per-wave
// 128x64 output = acc[4][2] of 32x32 -> 6 LDS reads per 8 MFMAs. K=512 = 4 tiles of 128;
// single 64KB LDS buffer, next tile prefetched into regs across the compute phase.
__global__ __launch_bounds__(512, 2) void k_gram(
    const unsigned short* __restrict__ xp, float* __restrict__ gpart) {
  const int swz = (blockIdx.x & 7) * 32 + (blockIdx.x >> 3);
  const int b   = swz >> 5;
  const int ck  = swz & 31;
  const char* tb0 = (const char*)xp + (size_t)b * XPB + (size_t)(ck * 4) * 65536;

  __shared__ __align__(16) char smem[65536];

  const int t    = threadIdx.x;
  const int lane = t & 63;
  const int w    = t >> 6;
  const int wm = w >> 2, wn = w & 3;     // wave tile: rows wm*128, cols wn*64
  const int ln = lane & 31, kh = lane >> 5;

  f32x16 acc[4][2];
#pragma unroll
  for (int m = 0; m < 4; ++m)
#pragma unroll
    for (int n = 0; n < 2; ++n)
#pragma unroll
      for (int i = 0; i < 16; ++i) acc[m][n][i] = 0.f;

  u16x8 ldreg[8];
#pragma unroll
  for (int r = 0; r < 8; ++r)
    ldreg[r] = *(const u16x8*)(tb0 + (size_t)t * 128 + r * 16);

  for (int kt = 0; kt < 4; ++kt) {
    __syncthreads();                     // previous compute done; buffer free
#pragma unroll
    for (int r = 0; r < 8; ++r)
      *(u16x8*)(smem + t * 128 + r * 16) = ldreg[r];
    __syncthreads();
    if (kt < 3) {                        // prefetch next tile; in flight across MFMA
#pragma unroll
      for (int r = 0; r < 8; ++r)
        ldreg[r] = *(const u16x8*)(tb0 + (size_t)(kt + 1) * 65536 + (size_t)t * 128 + r * 16);
    }
#pragma unroll
    for (int ch = 0; ch < 8; ++ch) {
      const int cp = ch * 2 + kh;        // 16B k-chunk index
      u16x8 A[4], Bv[2];
#pragma unroll
      for (int m = 0; m < 4; ++m) {
        int r = wm * 128 + m * 32 + ln;
        A[m] = *(const u16x8*)(smem + r * 256 + ((cp ^ (r & 15)) << 4));
      }
#pragma unroll
      for (int n = 0; n < 2; ++n) {
        int r = wn * 64 + n * 32 + ln;
        Bv[n] = *(const u16x8*)(smem + r * 256 + ((cp ^ (r & 15)) << 4));
      }
#pragma unroll
      for (int m = 0; m < 4; ++m)
#pragma unroll
        for (int n = 0; n < 2; ++n)
          acc[m][n] = mfma16h(A[m], Bv[n], acc[m][n]);
    }
  }

  float* gp = gpart + (size_t)(b * NC + ck) * (Cn * Cn);
#pragma unroll
  for (int m = 0; m < 4; ++m)
#pragma unroll
    for (int n = 0; n < 2; ++n)
#pragma unroll
      for (int r2 = 0; r2 < 16; ++r2) {
        int row = wm * 128 + m * 32 + (r2 & 3) + 8 * (r2 >> 2) + 4 * kh;
        int col = wn * 64 + n * 32 + ln;
        gp[row * Cn + col] = acc[m][n][r2];
      }
}

// ---------------- K2 (k_misc, 8 blocks): wkT transpose, kN = Wk s + N bk ----------------
__global__ __launch_bounds__(256) void k_misc(
    const float* __restrict__ sv, const float* __restrict__ wk,
    const float* __restrict__ bk, float* __restrict__ wkT,
    float* __restrict__ kN) {
  const int bb = blockIdx.x, t = threadIdx.x;
  __shared__ float s_l[256];
  s_l[t] = sv[bb * Cn + t];
#pragma unroll
  for (int j = 0; j < 32; ++j) {
    int k = bb * 32 + j;
    wkT[k * Cn + t] = wk[t * Cn + k];
  }
  __syncthreads();
  float k2 = 0.f;
  for (int c = 0; c < 256; ++c) k2 += wk[t * Cn + c] * s_l[c];
  kN[bb * Cn + t] = k2 + 16384.f * bk[t];
}

// ---------------- K3 (k_gk): GK = (sum gpart) @ WkT + s*bk^T  (fp32 VALU) ----------------
__global__ __launch_bounds__(256) void k_gk(
    const float* __restrict__ gpart, const float* __restrict__ sv,
    const float* __restrict__ wkT, const float* __restrict__ bk,
    float* __restrict__ GK) {
  const int b = blockIdx.x >> 6, tile = blockIdx.x & 63;
  const int r0 = tile * 4, t = threadIdx.x;
  __shared__ float g_l[4][256];

  float a[4] = {0.f, 0.f, 0.f, 0.f};
  const float* gp = gpart + (size_t)b * NC * 65536 + r0 * 256 + t;
  for (int ck = 0; ck < NC; ++ck) {
#pragma unroll
    for (int j = 0; j < 4; ++j) a[j] += gp[(size_t)ck * 65536 + j * 256];
  }
#pragma unroll
  for (int j = 0; j < 4; ++j) g_l[j][t] = a[j];
  __syncthreads();

  float acc[4] = {0.f, 0.f, 0.f, 0.f};
  for (int k0 = 0; k0 < 256; k0 += 4) {
    float w0 = wkT[(k0 + 0) * 256 + t];
    float w1 = wkT[(k0 + 1) * 256 + t];
    float w2 = wkT[(k0 + 2) * 256 + t];
    float w3 = wkT[(k0 + 3) * 256 + t];
#pragma unroll
    for (int r = 0; r < 4; ++r) {
      f32x4 gv = *(const f32x4*)(&g_l[r][k0]);
      acc[r] += gv.x * w0 + gv.y * w1 + gv.z * w2 + gv.w * w3;
    }
  }
  float bkt = bk[t];
#pragma unroll
  for (int r = 0; r < 4; ++r) {
    float svr = sv[b * 256 + r0 + r];
    GK[((size_t)b * 256 + r0 + r) * 256 + t] = acc[r] + svr * bkt;
  }
}

// ---------------- K4 (k_scores): scores = Wq@GK + bq*kN^T; softmax; ccB(+I) bf16 ----------------
__global__ __launch_bounds__(256) void k_scores(
    const float* __restrict__ wq, const float* __restrict__ GK,
    const float* __restrict__ bq, const float* __restrict__ kN,
    unsigned short* __restrict__ ccB) {
  const int b    = blockIdx.x >> 5;
  const int tile = blockIdx.x & 31;
  const int c0   = tile * 8;
  const int t    = threadIdx.x;

  __shared__ float wq_l[8][256];
  __shared__ float sc_l[8][256];
  __shared__ unsigned short cct_l[256][8];

#pragma unroll
  for (int j = 0; j < 8; ++j) wq_l[j][t] = wq[(c0 + j) * Cn + t];
  __syncthreads();

  float acc[8];
#pragma unroll
  for (int r = 0; r < 8; ++r) acc[r] = 0.f;
  for (int k0 = 0; k0 < 256; k0 += 4) {
    float g0 = GK[((size_t)b * 256 + k0 + 0) * 256 + t];
    float g1 = GK[((size_t)b * 256 + k0 + 1) * 256 + t];
    float g2 = GK[((size_t)b * 256 + k0 + 2) * 256 + t];
    float g3 = GK[((size_t)b * 256 + k0 + 3) * 256 + t];
#pragma unroll
    for (int r = 0; r < 8; ++r) {
      f32x4 qv = *(const f32x4*)(&wq_l[r][k0]);
      acc[r] += qv.x * g0 + qv.y * g1 + qv.z * g2 + qv.w * g3;
    }
  }
  float kNt = kN[b * 256 + t];
#pragma unroll
  for (int r = 0; r < 8; ++r) sc_l[r][t] = acc[r] + bq[c0 + r] * kNt;
  __syncthreads();

  const int r = t >> 5, sub = t & 31;
  float v[8];
#pragma unroll
  for (int j = 0; j < 8; ++j) v[j] = sc_l[r][sub + 32 * j];
  float mx = v[0];
#pragma unroll
  for (int j = 1; j < 8; ++j) mx = fmaxf(mx, v[j]);
#pragma unroll
  for (int msk = 16; msk >= 1; msk >>= 1) mx = fmaxf(mx, __shfl_xor(mx, msk, 32));
  float se = 0.f;
#pragma unroll
  for (int j = 0; j < 8; ++j) { v[j] = __expf(v[j] - mx); se += v[j]; }
#pragma unroll
  for (int msk = 16; msk >= 1; msk >>= 1) se += __shfl_xor(se, msk, 32);
  float inv = 1.f / se;
#pragma unroll
  for (int j = 0; j < 8; ++j) {
    int d = sub + 32 * j;
    float cc = v[j] * inv + ((d == c0 + r) ? 1.f : 0.f);   // fold residual: cc + I
    cct_l[d][r] = f2bf(cc);
  }
  __syncthreads();
  *(uint4*)(ccB + (size_t)b * 65536 + (size_t)(tile * 256 + t) * 8) =
      *(const uint4*)(&cct_l[t][0]);
}

// ---------------- K5 (k_out): out = x_bf16 @ (cc + I), XCD-chunked (1 batch/XCD) ----------
__global__ __launch_bounds__(256, 4) void k_out(
    const float* __restrict__ x, const unsigned short* __restrict__ ccB,
    float* __restrict__ out) {
  const int swz = (blockIdx.x & 7) * 256 + (blockIdx.x >> 3);
  const int b  = swz >> 8;
  const int n0 = (swz & 255) * 64;
  const float* xb = x + (size_t)b * Nn * Cn + (size_t)n0 * Cn;
  const unsigned short* cb = ccB + (size_t)b * 65536;
  float* ob = out + (size_t)b * Nn * Cn + (size_t)n0 * Cn;

  __shared__ __align__(16) char smem[32768];   // [64 rows][512B] bf16, XOR-swizzled

  const int t    = threadIdx.x;
  const int lane = t & 63;
  const int w    = t >> 6;
  const int ln = lane & 31;
  const int kh = lane >> 5;

  f32x16 acc[2][2];
#pragma unroll
  for (int m = 0; m < 2; ++m)
#pragma unroll
    for (int n = 0; n < 2; ++n)
#pragma unroll
      for (int i = 0; i < 16; ++i) acc[m][n][i] = 0.f;

#pragma unroll
  for (int i = 0; i < 16; ++i) {
    int fi = i * 256 + t;
    f32x4 v = *(const f32x4*)(xb + (size_t)fi * 4);
    int row = fi >> 6, c = fi & 63;
    ushort4 hv = make_ushort4(f2bf(v.x), f2bf(v.y), f2bf(v.z), f2bf(v.w));
    *(ushort4*)(smem + row * 512 + ((c * 8) ^ ((row & 31) << 4))) = hv;
  }
  __syncthreads();

#pragma unroll
  for (int ks = 0; ks < 16; ++ks) {
    u16x8 A[2], Bv[2];
    const int g = ks * 2 + kh;
#pragma unroll
    for (int m = 0; m < 2; ++m) {
      int row = m * 32 + ln;
      A[m] = *(const u16x8*)(smem + row * 512 + ((g * 16) ^ ((row & 31) << 4)));
    }
#pragma unroll
    for (int n = 0; n < 2; ++n) {
      int d = w * 64 + n * 32 + ln;
      Bv[n] = *(const u16x8*)(cb + (size_t)g * 2048 + (size_t)d * 8);
    }
#pragma unroll
    for (int m = 0; m < 2; ++m)
#pragma unroll
      for (int n = 0; n < 2; ++n)
        acc[m][n] = mfma16b(A[m], Bv[n], acc[m][n]);
  }

#pragma unroll
  for (int m = 0; m < 2; ++m)
#pragma unroll
    for (int n = 0; n < 2; ++n)
#pragma unroll
      for (int r2 = 0; r2 < 16; ++r2) {
        int row = m * 32 + (r2 & 3) + 8 * (r2 >> 2) + 4 * kh;
        int col = w * 64 + n * 32 + ln;
        ob[(size_t)row * Cn + col] = acc[m][n][r2];
      }
}

extern "C" void kernel_launch(void* const* d_in, const int* in_sizes, int n_in,
                              void* d_out, int out_size, void* d_ws, size_t ws_size,
                              hipStream_t stream) {
  const float* x  = (const float*)d_in[0];
  const float* wq = (const float*)d_in[1];
  const float* bq = (const float*)d_in[2];
  const float* wk = (const float*)d_in[3];
  const float* bk = (const float*)d_in[4];
  float* out = (float*)d_out;

  unsigned short* xp = (unsigned short*)d_ws;                    // 67MB packed fp16 tiles
  float* gpart = (float*)((char*)d_ws + (size_t)Bn * XPB);       // [B][NC][256][256] 64MB
  float* sv    = gpart + (size_t)Bn * NC * 65536;                // [B][256] (atomic)
  float* wkT   = sv + (size_t)Bn * 256;                          // [256][256]
  float* kN    = wkT + 65536;                                    // [B][256]
  float* GK    = kN + (size_t)Bn * 256;                          // [B][256][256]
  unsigned short* ccB = (unsigned short*)(GK + (size_t)Bn * 65536); // [B][32][256][8] bf16

  hipMemsetAsync(sv, 0, (size_t)Bn * 256 * sizeof(float), stream);
  hipLaunchKernelGGL(k_pack,   dim3(Bn * 128), dim3(256), 0, stream, x, xp, sv);
  hipLaunchKernelGGL(k_gram,   dim3(Bn * NC),  dim3(512), 0, stream, xp, gpart);
  hipLaunchKernelGGL(k_misc,   dim3(Bn),       dim3(256), 0, stream, sv, wk, bk, wkT, kN);
  hipLaunchKernelGGL(k_gk,     dim3(Bn * 64),  dim3(256), 0, stream, gpart, sv, wkT, bk, GK);
  hipLaunchKernelGGL(k_scores, dim3(Bn * 32),  dim3(256), 0, stream, wq, GK, bq, kN, ccB);
  hipLaunchKernelGGL(k_out,    dim3(Bn * 256), dim3(256), 0, stream, x, ccB, out);
}